// Round 3
// baseline (9833.430 us; speedup 1.0000x reference)
//
#include <hip/hip_runtime.h>
#include <hip/hip_bf16.h>
#include <stdint.h>

// Problem constants
#define B_    64
#define LC_   512
#define LPV_  16
#define LTP_  16
#define V_    8192
#define H_    1024
#define PREF_ 16
#define S_    545          // LC + LPV + LTP + 1
#define NEGV  (-1e9f)
#define INV32 0.03125f     // H^-0.5 = 1/32 (exact)

// ---------------- threefry2x32 (exact JAX semantics) ----------------
__device__ __forceinline__ uint32_t rotl32(uint32_t x, uint32_t d){ return (x<<d)|(x>>(32u-d)); }

__device__ __forceinline__ void tf2x32(uint32_t k0, uint32_t k1, uint32_t& x0, uint32_t& x1){
  uint32_t ks0=k0, ks1=k1, ks2=k0^k1^0x1BD11BDAu;
  x0+=ks0; x1+=ks1;
  x0+=x1; x1=rotl32(x1,13); x1^=x0;
  x0+=x1; x1=rotl32(x1,15); x1^=x0;
  x0+=x1; x1=rotl32(x1,26); x1^=x0;
  x0+=x1; x1=rotl32(x1, 6); x1^=x0;
  x0+=ks1; x1+=ks2+1u;
  x0+=x1; x1=rotl32(x1,17); x1^=x0;
  x0+=x1; x1=rotl32(x1,29); x1^=x0;
  x0+=x1; x1=rotl32(x1,16); x1^=x0;
  x0+=x1; x1=rotl32(x1,24); x1^=x0;
  x0+=ks2; x1+=ks0+2u;
  x0+=x1; x1=rotl32(x1,13); x1^=x0;
  x0+=x1; x1=rotl32(x1,15); x1^=x0;
  x0+=x1; x1=rotl32(x1,26); x1^=x0;
  x0+=x1; x1=rotl32(x1, 6); x1^=x0;
  x0+=ks0; x1+=ks1+3u;
  x0+=x1; x1=rotl32(x1,17); x1^=x0;
  x0+=x1; x1=rotl32(x1,29); x1^=x0;
  x0+=x1; x1=rotl32(x1,16); x1^=x0;
  x0+=x1; x1=rotl32(x1,24); x1^=x0;
  x0+=ks1; x1+=ks2+4u;
  x0+=x1; x1=rotl32(x1,13); x1^=x0;
  x0+=x1; x1=rotl32(x1,15); x1^=x0;
  x0+=x1; x1=rotl32(x1,26); x1^=x0;
  x0+=x1; x1=rotl32(x1, 6); x1^=x0;
  x0+=ks2; x1+=ks0+5u;
}

// ---------------- init y0 = one_hot(BOS=2) ----------------
__global__ void init_y0(float* __restrict__ y0){
  int idx = blockIdx.x*256 + threadIdx.x;        // grid 2048 -> 524288
  y0[idx] = ((idx & (V_-1)) == 2) ? 1.f : 0.f;
}

// ---------------- generic 64x64-tile fp32 GEMM ----------------
// C[M x N] = A[M x K] @ (TRANSB ? B^T : B), row-major.
// ATOMIC: split-K over blockIdx.z (kchunk per z), atomicAdd into pre-zeroed C.
// C2 (optional): duplicate destination (used to seed t1 = emb).
// BIAS: += bias[col] (only z==0). ATANH: tanh() applied to A elements on load.
template<bool TRANSB, bool ATOMIC, bool BIAS, bool ATANH>
__global__ __launch_bounds__(256) void gemm64(
    const float* __restrict__ A, int lda,
    const float* __restrict__ B, int ldb,
    float* __restrict__ C, float* __restrict__ C2, int ldc,
    int K, int kchunk, const float* __restrict__ bias)
{
  __shared__ __align__(16) float Alt[64][68];   // [kk][row]
  __shared__ __align__(16) float Bl [64][68];   // [kk][col]
  const int t  = threadIdx.x;
  const int tx = t & 15, ty = t >> 4;
  const int col0 = blockIdx.x * 64, row0 = blockIdx.y * 64;
  const int k0   = ATOMIC ? blockIdx.z * kchunk : 0;
  const int kend = ATOMIC ? (k0 + kchunk) : K;
  float acc[4][4];
  #pragma unroll
  for (int i=0;i<4;i++){
    #pragma unroll
    for (int j=0;j<4;j++) acc[i][j]=0.f;
  }
  const int lr = t >> 2, lq = (t & 3) * 16;
  for (int kb = k0; kb < kend; kb += 64){
    {
      const float* Ap = A + (size_t)(row0+lr)*lda + kb + lq;
      float4 a0 = *(const float4*)(Ap+0);
      float4 a1 = *(const float4*)(Ap+4);
      float4 a2 = *(const float4*)(Ap+8);
      float4 a3 = *(const float4*)(Ap+12);
      if (ATANH){
        a0.x=tanhf(a0.x); a0.y=tanhf(a0.y); a0.z=tanhf(a0.z); a0.w=tanhf(a0.w);
        a1.x=tanhf(a1.x); a1.y=tanhf(a1.y); a1.z=tanhf(a1.z); a1.w=tanhf(a1.w);
        a2.x=tanhf(a2.x); a2.y=tanhf(a2.y); a2.z=tanhf(a2.z); a2.w=tanhf(a2.w);
        a3.x=tanhf(a3.x); a3.y=tanhf(a3.y); a3.z=tanhf(a3.z); a3.w=tanhf(a3.w);
      }
      Alt[lq+ 0][lr]=a0.x; Alt[lq+ 1][lr]=a0.y; Alt[lq+ 2][lr]=a0.z; Alt[lq+ 3][lr]=a0.w;
      Alt[lq+ 4][lr]=a1.x; Alt[lq+ 5][lr]=a1.y; Alt[lq+ 6][lr]=a1.z; Alt[lq+ 7][lr]=a1.w;
      Alt[lq+ 8][lr]=a2.x; Alt[lq+ 9][lr]=a2.y; Alt[lq+10][lr]=a2.z; Alt[lq+11][lr]=a2.w;
      Alt[lq+12][lr]=a3.x; Alt[lq+13][lr]=a3.y; Alt[lq+14][lr]=a3.z; Alt[lq+15][lr]=a3.w;
    }
    if (TRANSB){
      const float* Bp = B + (size_t)(col0+lr)*ldb + kb + lq;
      float4 b0 = *(const float4*)(Bp+0);
      float4 b1 = *(const float4*)(Bp+4);
      float4 b2 = *(const float4*)(Bp+8);
      float4 b3 = *(const float4*)(Bp+12);
      Bl[lq+ 0][lr]=b0.x; Bl[lq+ 1][lr]=b0.y; Bl[lq+ 2][lr]=b0.z; Bl[lq+ 3][lr]=b0.w;
      Bl[lq+ 4][lr]=b1.x; Bl[lq+ 5][lr]=b1.y; Bl[lq+ 6][lr]=b1.z; Bl[lq+ 7][lr]=b1.w;
      Bl[lq+ 8][lr]=b2.x; Bl[lq+ 9][lr]=b2.y; Bl[lq+10][lr]=b2.z; Bl[lq+11][lr]=b2.w;
      Bl[lq+12][lr]=b3.x; Bl[lq+13][lr]=b3.y; Bl[lq+14][lr]=b3.z; Bl[lq+15][lr]=b3.w;
    } else {
      const int bk = t >> 2;
      const int bc = (t & 3) * 16;
      const float* Bp = B + (size_t)(kb+bk)*ldb + col0 + bc;
      float4 b0 = *(const float4*)(Bp+0);
      float4 b1 = *(const float4*)(Bp+4);
      float4 b2 = *(const float4*)(Bp+8);
      float4 b3 = *(const float4*)(Bp+12);
      *(float4*)&Bl[bk][bc+ 0] = b0;
      *(float4*)&Bl[bk][bc+ 4] = b1;
      *(float4*)&Bl[bk][bc+ 8] = b2;
      *(float4*)&Bl[bk][bc+12] = b3;
    }
    __syncthreads();
    #pragma unroll 4
    for (int kk=0; kk<64; kk++){
      float4 av = *(const float4*)&Alt[kk][ty*4];
      float4 bv = *(const float4*)&Bl [kk][tx*4];
      acc[0][0] += av.x*bv.x; acc[0][1] += av.x*bv.y; acc[0][2] += av.x*bv.z; acc[0][3] += av.x*bv.w;
      acc[1][0] += av.y*bv.x; acc[1][1] += av.y*bv.y; acc[1][2] += av.y*bv.z; acc[1][3] += av.y*bv.w;
      acc[2][0] += av.z*bv.x; acc[2][1] += av.z*bv.y; acc[2][2] += av.z*bv.z; acc[2][3] += av.z*bv.w;
      acc[3][0] += av.w*bv.x; acc[3][1] += av.w*bv.y; acc[3][2] += av.w*bv.z; acc[3][3] += av.w*bv.w;
    }
    __syncthreads();
  }
  #pragma unroll
  for (int i=0;i<4;i++){
    const int r = row0 + ty*4 + i;
    #pragma unroll
    for (int j=0;j<4;j++){
      const int cc = col0 + tx*4 + j;
      size_t idx = (size_t)r*ldc + cc;
      float v = acc[i][j];
      if (BIAS){ if (!ATOMIC || blockIdx.z==0) v += bias[cc]; }
      if (ATOMIC){
        atomicAdd(&C[idx], v);
        if (C2) atomicAdd(&C2[idx], v);
      } else {
        C[idx] = v;
        if (C2) C2[idx] = v;
      }
    }
  }
}

// ---------------- virtual src_hidden row resolver ----------------
__device__ __forceinline__ const float* resolve_row(
    int b, int j, float& mval,
    const float* __restrict__ E_ctx, const int* __restrict__ context, const int* __restrict__ ctx_len,
    const float* __restrict__ pvh, const float* __restrict__ pv_mask,
    const float* __restrict__ tp_hidden, const int* __restrict__ tp_len,
    const float* __restrict__ ar_hidden, const int* __restrict__ ar_len)
{
  if (j < 512){ mval = (j < ctx_len[b]) ? 1.f : 0.f; return E_ctx + (size_t)context[b*LC_+j]*H_; }
  else if (j < 528){ int l=j-512; mval = pv_mask[b*LPV_+l]; return pvh + (size_t)(b*LPV_+l)*H_; }
  else if (j < 544){ int l=j-528; mval = (l < tp_len[b]) ? 1.f : 0.f; return tp_hidden + (size_t)(b*LTP_+l)*H_; }
  else { mval = (ar_len[b] > 0) ? 1.f : 0.f; return ar_hidden + (size_t)b*H_; }
}

// ---------------- attention: s = qk . src/32, masked softmax, asrc = a . src ----------------
__global__ __launch_bounds__(256) void attn_kernel(
    const float* __restrict__ qk,
    const float* __restrict__ E_ctx, const int* __restrict__ context, const int* __restrict__ ctx_len,
    const float* __restrict__ pvh, const float* __restrict__ pv_mask,
    const float* __restrict__ tp_hidden, const int* __restrict__ tp_len,
    const float* __restrict__ ar_hidden, const int* __restrict__ ar_len,
    float* __restrict__ asrc)
{
  const int b = blockIdx.x, t = threadIdx.x;
  __shared__ __align__(16) float4 qk_lds[256];
  __shared__ const float* rp[S_];
  __shared__ float sv[S_];
  __shared__ float red[4];
  qk_lds[t] = ((const float4*)(qk + (size_t)b*H_))[t];
  __syncthreads();
  const int w = t>>6, lane = t&63;
  for (int j = w; j < S_; j += 4){
    float mval;
    const float* row = resolve_row(b, j, mval, E_ctx, context, ctx_len, pvh, pv_mask, tp_hidden, tp_len, ar_hidden, ar_len);
    if (lane == 0) rp[j] = row;
    float s;
    if (mval != 0.f){
      const float4* r4 = (const float4*)row;
      float acc = 0.f;
      #pragma unroll
      for (int i=0;i<4;i++){
        float4 a = r4[lane + 64*i]; float4 q = qk_lds[lane + 64*i];
        acc += a.x*q.x + a.y*q.y + a.z*q.z + a.w*q.w;
      }
      #pragma unroll
      for (int off=32; off; off>>=1) acc += __shfl_down(acc, off, 64);
      s = acc * INV32;
    } else s = NEGV;
    if (lane == 0) sv[j] = s;
  }
  __syncthreads();
  float lm = -3.4e38f;
  for (int j = t; j < S_; j += 256) lm = fmaxf(lm, sv[j]);
  #pragma unroll
  for (int off=32; off; off>>=1) lm = fmaxf(lm, __shfl_down(lm, off, 64));
  if (lane==0) red[w] = lm;
  __syncthreads();
  const float m = fmaxf(fmaxf(red[0],red[1]), fmaxf(red[2],red[3]));
  __syncthreads();
  float ls = 0.f;
  for (int j = t; j < S_; j += 256){ float e = expf(sv[j] - m); sv[j] = e; ls += e; }
  #pragma unroll
  for (int off=32; off; off>>=1) ls += __shfl_down(ls, off, 64);
  if (lane==0) red[w] = ls;
  __syncthreads();
  const float Z = red[0]+red[1]+red[2]+red[3];
  for (int j = t; j < S_; j += 256) sv[j] = sv[j] / Z;
  __syncthreads();
  float4 acc4 = {0.f,0.f,0.f,0.f};
  for (int j = 0; j < S_; j++){
    float wgt = sv[j];
    if (wgt != 0.f){
      float4 r = ((const float4*)rp[j])[t];
      acc4.x += wgt*r.x; acc4.y += wgt*r.y; acc4.z += wgt*r.z; acc4.w += wgt*r.w;
    }
  }
  ((float4*)(asrc + (size_t)b*H_))[t] = acc4;
}

// ---------------- copy logits (scaled) + global softmax max/Z over 8736 ----------------
__global__ __launch_bounds__(256) void copy_kernel(
    const float* __restrict__ decr, const float* __restrict__ gen,
    const float* __restrict__ E_ctx, const int* __restrict__ context, const int* __restrict__ ctx_len,
    const float* __restrict__ pvh, const float* __restrict__ pv_mask,
    const float* __restrict__ tp_hidden, const int* __restrict__ tp_len,
    const float* __restrict__ ar_hidden, const int* __restrict__ ar_len,
    float* __restrict__ cl, float* __restrict__ mz)
{
  const int b = blockIdx.x, t = threadIdx.x;
  __shared__ __align__(16) float4 dec_lds[256];
  __shared__ float sv[544];
  __shared__ float red[4];
  {
    float4 d = ((const float4*)(decr + (size_t)b*H_))[t];
    d.x = tanhf(d.x); d.y = tanhf(d.y); d.z = tanhf(d.z); d.w = tanhf(d.w);
    dec_lds[t] = d;
  }
  __syncthreads();
  const int w = t>>6, lane = t&63;
  for (int j = w; j < 544; j += 4){
    float mval;
    const float* row = resolve_row(b, j, mval, E_ctx, context, ctx_len, pvh, pv_mask, tp_hidden, tp_len, ar_hidden, ar_len);
    float s;
    if (mval != 0.f){
      const float4* r4 = (const float4*)row;
      float acc = 0.f;
      #pragma unroll
      for (int i=0;i<4;i++){
        float4 a = r4[lane + 64*i]; float4 q = dec_lds[lane + 64*i];
        acc += a.x*q.x + a.y*q.y + a.z*q.z + a.w*q.w;
      }
      #pragma unroll
      for (int off=32; off; off>>=1) acc += __shfl_down(acc, off, 64);
      s = acc * INV32;
    } else s = NEGV * INV32;   // matches ref: NEG then *H^-0.5
    if (lane == 0) sv[j] = s;
  }
  __syncthreads();
  float gv[32];
  float lm = -3.4e38f;
  const float4* g4 = (const float4*)(gen + (size_t)b*V_);
  #pragma unroll
  for (int i=0;i<8;i++){
    float4 g = g4[t + 256*i];
    gv[4*i+0]=g.x*INV32; gv[4*i+1]=g.y*INV32; gv[4*i+2]=g.z*INV32; gv[4*i+3]=g.w*INV32;
    lm = fmaxf(lm, fmaxf(fmaxf(gv[4*i],gv[4*i+1]), fmaxf(gv[4*i+2],gv[4*i+3])));
  }
  for (int j = t; j < 544; j += 256) lm = fmaxf(lm, sv[j]);
  #pragma unroll
  for (int off=32; off; off>>=1) lm = fmaxf(lm, __shfl_down(lm, off, 64));
  if (lane==0) red[w] = lm;
  __syncthreads();
  const float m = fmaxf(fmaxf(red[0],red[1]), fmaxf(red[2],red[3]));
  __syncthreads();
  float ls = 0.f;
  #pragma unroll
  for (int i=0;i<32;i++) ls += expf(gv[i] - m);
  for (int j = t; j < 544; j += 256) ls += expf(sv[j] - m);
  #pragma unroll
  for (int off=32; off; off>>=1) ls += __shfl_down(ls, off, 64);
  if (lane==0) red[w] = ls;
  __syncthreads();
  const float Z = red[0]+red[1]+red[2]+red[3];
  for (int j = t; j < 544; j += 256) cl[b*544 + j] = sv[j];
  if (t == 0){ mz[2*b] = m; mz[2*b+1] = Z; }
}

// ---------------- p = gen_prob + copy_pv_p (dense part), write out0 ----------------
__global__ __launch_bounds__(256) void pbuild_kernel(
    const float* __restrict__ gen, const float* __restrict__ cl, const float* __restrict__ mz,
    const float* __restrict__ pv_m, float* __restrict__ out0, int step)
{
  const int b = blockIdx.x, ch = blockIdx.y, t = threadIdx.x;
  __shared__ float pvp[16];
  const float m = mz[2*b], Z = mz[2*b+1];
  if (t < 16) pvp[t] = expf(cl[b*544 + 512 + t] - m) / Z;
  __syncthreads();
  const int f4i = ch*256 + t;
  float4 g = ((const float4*)(gen + (size_t)b*V_))[f4i];
  float4 pb;
  pb.x = expf(g.x*INV32 - m)/Z;
  pb.y = expf(g.y*INV32 - m)/Z;
  pb.z = expf(g.z*INV32 - m)/Z;
  pb.w = expf(g.w*INV32 - m)/Z;
  #pragma unroll
  for (int l=0;l<16;l++){
    float wgt = pvp[l];
    float4 q = ((const float4*)(pv_m + (size_t)(b*LPV_+l)*V_))[f4i];
    pb.x += wgt*q.x; pb.y += wgt*q.y; pb.z += wgt*q.z; pb.w += wgt*q.w;
  }
  ((float4*)(out0 + (size_t)(b*PREF_+step)*V_))[f4i] = pb;
}

// ---------------- scatter: ccopy (ctx via glo2loc) + copy_tp ----------------
__global__ __launch_bounds__(256) void scatter_kernel(
    const float* __restrict__ cl, const float* __restrict__ mz,
    const int* __restrict__ context, const int* __restrict__ glo2loc, const int* __restrict__ tp_path,
    float* __restrict__ out0, int step)
{
  const int b = blockIdx.x, t = threadIdx.x;
  const float m = mz[2*b], Z = mz[2*b+1];
  float* dst = out0 + (size_t)(b*PREF_+step)*V_;
  for (int jj = t; jj < 528; jj += 256){
    float val; int tgt;
    if (jj < 512){
      val = expf(cl[b*544 + jj] - m) / Z;
      tgt = glo2loc[context[b*LC_ + jj]];
    } else {
      int l = jj - 512;
      val = expf(cl[b*544 + 528 + l] - m) / Z;
      tgt = tp_path[b*LTP_ + l];
    }
    if (val != 0.f) atomicAdd(dst + tgt, val);
  }
}

// ---------------- gumbel-softmax sampling (JAX threefry, partitionable layout) ----------------
// jax_threefry_partitionable=True (modern default): element flat index j becomes the
// 64-bit counter (hi=0, lo=j); bits1,bits2 = threefry2x32(key_t, (0, j)); for
// bit_width<=32 the partitionable path returns bits1 ^ bits2 (XOR-fold of the block).
__global__ __launch_bounds__(256) void sample_kernel(
    const float* __restrict__ out0, float* __restrict__ out1, int step)
{
  const int b = blockIdx.x, t = threadIdx.x;
  __shared__ float red[4];
  // key_t = threefry_2x32(key(42)=[0,42], [0, step])   (fold_in is config-independent)
  uint32_t kx = 0u, ky = (uint32_t)step;
  tf2x32(0u, 42u, kx, ky);
  const float* p = out0 + (size_t)(b*PREF_ + step)*V_;
  float lv[32];
  float lm = -3.4e38f;
  #pragma unroll
  for (int i=0;i<32;i++){
    int v = t + 256*i;
    float pv = p[v];
    uint32_t j = (uint32_t)(b*V_ + v);
    uint32_t x0 = 0u, x1 = j;            // counter = (j>>32, j&0xffffffff) = (0, j)
    tf2x32(kx, ky, x0, x1);
    uint32_t bits = x0 ^ x1;             // XOR-fold of the two output words
    float f = __uint_as_float((bits >> 9) | 0x3F800000u) - 1.0f;
    float u = fmaxf(1e-10f, f + 1e-10f); // (maxval-minval) rounds to exactly 1.0f
    float g = -logf(-logf(u));
    float l = (logf(pv + 1e-10f) + g) / 0.67f;
    lv[i] = l;
    lm = fmaxf(lm, l);
  }
  const int w = t>>6, lane = t&63;
  #pragma unroll
  for (int off=32; off; off>>=1) lm = fmaxf(lm, __shfl_down(lm, off, 64));
  if (lane==0) red[w] = lm;
  __syncthreads();
  const float m = fmaxf(fmaxf(red[0],red[1]), fmaxf(red[2],red[3]));
  __syncthreads();
  float ls = 0.f;
  #pragma unroll
  for (int i=0;i<32;i++){ lv[i] = expf(lv[i] - m); ls += lv[i]; }
  #pragma unroll
  for (int off=32; off; off>>=1) ls += __shfl_down(ls, off, 64);
  if (lane==0) red[w] = ls;
  __syncthreads();
  const float Z = red[0]+red[1]+red[2]+red[3];
  float* y = out1 + (size_t)(b*PREF_ + step)*V_;
  #pragma unroll
  for (int i=0;i<32;i++) y[t + 256*i] = lv[i] / Z;
}

// ---------------- host ----------------
extern "C" void kernel_launch(void* const* d_in, const int* in_sizes, int n_in,
                              void* d_out, int out_size, void* d_ws, size_t ws_size,
                              hipStream_t stream)
{
  (void)in_sizes; (void)n_in; (void)out_size; (void)ws_size;
  const int*   context   = (const int*)  d_in[0];
  const int*   ctx_len   = (const int*)  d_in[1];
  const float* pv_m      = (const float*)d_in[2];
  const float* pv_mask   = (const float*)d_in[3];
  const int*   ar_len    = (const int*)  d_in[5];
  const int*   tp_path   = (const int*)  d_in[6];
  const int*   tp_len    = (const int*)  d_in[7];
  const float* tp_hidden = (const float*)d_in[8];
  const float* ar_hidden = (const float*)d_in[9];
  const float* E_ctx     = (const float*)d_in[10];
  const float* W_p       = (const float*)d_in[11];
  const float* E_topic   = (const float*)d_in[12];
  const float* W_q       = (const float*)d_in[13];
  const float* W_k       = (const float*)d_in[14];
  const float* W_v       = (const float*)d_in[15];
  const float* W_o       = (const float*)d_in[16];
  const float* gen_W     = (const float*)d_in[17];
  const float* gen_b     = (const float*)d_in[18];
  const int*   glo2loc   = (const int*)  d_in[19];

  float* out0 = (float*)d_out;
  float* out1 = out0 + (size_t)B_*PREF_*V_;

  float* ws   = (float*)d_ws;
  float* Mw   = ws;  ws += 1024*1024;     // W_q @ W_k^T
  float* pvh  = ws;  ws += 1024*1024;     // pv_hidden (B*LPV x H)
  float* y0   = ws;  ws += (size_t)B_*V_; // one-hot BOS
  float* emb  = ws;  ws += B_*H_;         // -- zero region start --
  float* qk   = ws;  ws += B_*H_;
  float* t1   = ws;  ws += B_*H_;
  float* decr = ws;  ws += B_*H_;         // pre-tanh dec
  float* gen  = ws;  ws += (size_t)B_*V_; // -- zero region end --
  float* asrc = ws;  ws += B_*H_;
  float* cl   = ws;  ws += B_*544;
  float* mz   = ws;  ws += 2*B_;
  const size_t zbytes = (size_t)(4*B_*H_ + B_*V_) * sizeof(float);

  // ---- one-time setup ----
  init_y0<<<dim3(2048), dim3(256), 0, stream>>>(y0);
  // M = W_q @ W_k^T
  gemm64<true,false,false,false><<<dim3(16,16,1), dim3(256), 0, stream>>>(
      W_q, H_, W_k, H_, Mw, (float*)nullptr, H_, H_, 0, nullptr);
  // pv_hidden = pv_m @ W_p   (rows = B*LPV = 1024, K = V)
  gemm64<false,false,false,false><<<dim3(16,16,1), dim3(256), 0, stream>>>(
      pv_m, V_, W_p, H_, pvh, (float*)nullptr, H_, V_, 0, nullptr);

  // ---- decode loop ----
  for (int t = 0; t < PREF_; ++t){
    hipMemsetAsync(emb, 0, zbytes, stream);
    const float* yprev = (t == 0) ? y0 : (out1 + (size_t)(t-1)*V_);
    const int    ylda  = (t == 0) ? V_ : PREF_*V_;
    // emb = y_prev @ E_topic (dual-write into t1 to seed t1 = emb)
    gemm64<false,true,false,false><<<dim3(16,1,16), dim3(256), 0, stream>>>(
        yprev, ylda, E_topic, H_, emb, t1, H_, V_, 512, nullptr);
    // qk = emb @ M
    gemm64<false,true,false,false><<<dim3(16,1,4), dim3(256), 0, stream>>>(
        emb, H_, Mw, H_, qk, (float*)nullptr, H_, H_, 256, nullptr);
    // attention -> asrc
    attn_kernel<<<dim3(64), dim3(256), 0, stream>>>(
        qk, E_ctx, context, ctx_len, pvh, pv_mask, tp_hidden, tp_len, ar_hidden, ar_len, asrc);
    // t1 += asrc @ W_v   (t1 = emb + ctx)
    gemm64<false,true,false,false><<<dim3(16,1,4), dim3(256), 0, stream>>>(
        asrc, H_, W_v, H_, t1, (float*)nullptr, H_, H_, 256, nullptr);
    // decr = t1 @ W_o    (tanh deferred to consumers)
    gemm64<false,true,false,false><<<dim3(16,1,4), dim3(256), 0, stream>>>(
        t1, H_, W_o, H_, decr, (float*)nullptr, H_, H_, 256, nullptr);
    // gen = tanh(decr) @ gen_W + gen_b
    gemm64<false,true,true,true><<<dim3(128,1,2), dim3(256), 0, stream>>>(
        decr, H_, gen_W, V_, gen, (float*)nullptr, V_, H_, 512, gen_b);
    // copy logits + softmax stats over 8736
    copy_kernel<<<dim3(64), dim3(256), 0, stream>>>(
        decr, gen, E_ctx, context, ctx_len, pvh, pv_mask, tp_hidden, tp_len, ar_hidden, ar_len, cl, mz);
    // dense p -> out0
    pbuild_kernel<<<dim3(64,8), dim3(256), 0, stream>>>(gen, cl, mz, pv_m, out0, t);
    // scatter ctx/tp copy mass
    scatter_kernel<<<dim3(64), dim3(256), 0, stream>>>(cl, mz, context, glo2loc, tp_path, out0, t);
    // gumbel-softmax sample -> out1 (= next y)
    sample_kernel<<<dim3(64), dim3(256), 0, stream>>>(out0, out1, t);
  }
}

// Round 4
// 3951.057 us; speedup vs baseline: 2.4888x; 2.4888x over previous
//
#include <hip/hip_runtime.h>
#include <hip/hip_bf16.h>
#include <stdint.h>

// Problem constants
#define B_    64
#define LC_   512
#define LPV_  16
#define LTP_  16
#define V_    8192
#define H_    1024
#define PREF_ 16
#define S_    545          // LC + LPV + LTP + 1
#define NEGV  (-1e9f)
#define INV32 0.03125f     // H^-0.5 = 1/32 (exact)

typedef __attribute__((ext_vector_type(8))) short s8v;   // 8 bf16 (4 VGPRs) MFMA A/B frag
typedef __attribute__((ext_vector_type(4))) float f4a;   // MFMA C/D frag

// fp32 -> bf16 (RNE), bit pattern in short
__device__ __forceinline__ short f2bf(float f){
  uint32_t u = __float_as_uint(f);
  uint32_t r = (u + 0x7fffu + ((u >> 16) & 1u)) >> 16;
  return (short)(r & 0xffffu);
}

// ---------------- threefry2x32 (exact JAX semantics) ----------------
__device__ __forceinline__ uint32_t rotl32(uint32_t x, uint32_t d){ return (x<<d)|(x>>(32u-d)); }

__device__ __forceinline__ void tf2x32(uint32_t k0, uint32_t k1, uint32_t& x0, uint32_t& x1){
  uint32_t ks0=k0, ks1=k1, ks2=k0^k1^0x1BD11BDAu;
  x0+=ks0; x1+=ks1;
  x0+=x1; x1=rotl32(x1,13); x1^=x0;
  x0+=x1; x1=rotl32(x1,15); x1^=x0;
  x0+=x1; x1=rotl32(x1,26); x1^=x0;
  x0+=x1; x1=rotl32(x1, 6); x1^=x0;
  x0+=ks1; x1+=ks2+1u;
  x0+=x1; x1=rotl32(x1,17); x1^=x0;
  x0+=x1; x1=rotl32(x1,29); x1^=x0;
  x0+=x1; x1=rotl32(x1,16); x1^=x0;
  x0+=x1; x1=rotl32(x1,24); x1^=x0;
  x0+=ks2; x1+=ks0+2u;
  x0+=x1; x1=rotl32(x1,13); x1^=x0;
  x0+=x1; x1=rotl32(x1,15); x1^=x0;
  x0+=x1; x1=rotl32(x1,26); x1^=x0;
  x0+=x1; x1=rotl32(x1, 6); x1^=x0;
  x0+=ks0; x1+=ks1+3u;
  x0+=x1; x1=rotl32(x1,17); x1^=x0;
  x0+=x1; x1=rotl32(x1,29); x1^=x0;
  x0+=x1; x1=rotl32(x1,16); x1^=x0;
  x0+=x1; x1=rotl32(x1,24); x1^=x0;
  x0+=ks1; x1+=ks2+4u;
  x0+=x1; x1=rotl32(x1,13); x1^=x0;
  x0+=x1; x1=rotl32(x1,15); x1^=x0;
  x0+=x1; x1=rotl32(x1,26); x1^=x0;
  x0+=x1; x1=rotl32(x1, 6); x1^=x0;
  x0+=ks2; x1+=ks0+5u;
}

// ---------------- init y0 = one_hot(BOS=2) ----------------
__global__ void init_y0(float* __restrict__ y0){
  int idx = blockIdx.x*256 + threadIdx.x;
  y0[idx] = ((idx & (V_-1)) == 2) ? 1.f : 0.f;
}

// ---------------- bf16 MFMA GEMM ----------------
// C[M x N] = A[M x K] @ (TRANSB ? B^T : B); fp32 in memory, bf16 in LDS/MFMA, fp32 out.
// BM in {64,128}, BN=128, BK=64. grid = (N/128, M/BM (1 if BM==64), zsplit).
// ATOMIC: split-K atomicAdd into pre-zeroed C (kchunk per z). C2: dual destination.
// BIAS: += bias[col] (z==0 only). ATANH: tanh() on A load.
// LDS k-packeted layout: P[k>>3][row][k&7] so an MFMA frag (8 consecutive k for one
// row, k0%8==0) is one 16B ds_read_b128; lanes l16=0..15 stride 16B -> 2-way bank
// aliasing only (free per m136).
template<int BM, bool TRANSB, bool ATOMIC, bool BIAS, bool ATANH>
__global__ __launch_bounds__(256) void mgemm(
    const float* __restrict__ A, int lda,
    const float* __restrict__ Bm, int ldb,
    float* __restrict__ C, float* __restrict__ C2, int ldc,
    int kchunk, const float* __restrict__ bias)
{
  constexpr int BN = 128, BK = 64;
  __shared__ short Ap[(BK/8)*BM*8];
  __shared__ short Bp[(BK/8)*BN*8];
  const int t = threadIdx.x;
  const int w = t >> 6, lane = t & 63;
  const int quad = lane >> 4, l16 = lane & 15;
  const int col0 = blockIdx.x * BN;
  const int row0 = (BM==128) ? blockIdx.y * BM : 0;
  const int k0 = blockIdx.z * kchunk, kend = k0 + kchunk;
  constexpr int MT = 2;
  constexpr int NT = (BM==128) ? 8 : 4;
  const int mbase = (BM==128) ? w*32 : (w&1)*32;
  const int nbase = (BM==128) ? 0 : (w>>1)*64;
  f4a acc[MT][NT];
  #pragma unroll
  for (int mt=0; mt<MT; mt++)
    #pragma unroll
    for (int nt=0; nt<NT; nt++)
      acc[mt][nt] = (f4a){0.f,0.f,0.f,0.f};

  for (int kb = k0; kb < kend; kb += BK){
    // ---- stage A (row-major [M][K] source) ----
    #pragma unroll
    for (int i = 0; i < BM*16/256; ++i){
      int idx = t + i*256;
      int m = idx >> 4, kq = (idx & 15) * 4;
      float4 a = *(const float4*)(A + (size_t)(row0+m)*lda + kb + kq);
      if (ATANH){ a.x=tanhf(a.x); a.y=tanhf(a.y); a.z=tanhf(a.z); a.w=tanhf(a.w); }
      short4 s4; s4.x=f2bf(a.x); s4.y=f2bf(a.y); s4.z=f2bf(a.z); s4.w=f2bf(a.w);
      *(short4*)&Ap[((kq>>3)*BM + m)*8 + (kq&7)] = s4;
    }
    // ---- stage B ----
    if (TRANSB){
      // source row-major [N][K]
      #pragma unroll
      for (int i = 0; i < 8; ++i){
        int idx = t + i*256;
        int n = idx >> 4, kq = (idx & 15) * 4;
        float4 bv = *(const float4*)(Bm + (size_t)(col0+n)*ldb + kb + kq);
        short4 s4; s4.x=f2bf(bv.x); s4.y=f2bf(bv.y); s4.z=f2bf(bv.z); s4.w=f2bf(bv.w);
        *(short4*)&Bp[((kq>>3)*BN + n)*8 + (kq&7)] = s4;
      }
    } else {
      // source row-major [K][N]: column chunks (4 k for one n), coalesced across threads
      #pragma unroll
      for (int c = 0; c < 8; ++c){
        int idx = t + c*256;
        int n = idx & 127, kq = (idx >> 7) * 4;
        const float* bp0 = Bm + (size_t)(kb+kq)*ldb + col0 + n;
        float b0 = bp0[0], b1 = bp0[ldb], b2 = bp0[2*(size_t)ldb], b3 = bp0[3*(size_t)ldb];
        short4 s4; s4.x=f2bf(b0); s4.y=f2bf(b1); s4.z=f2bf(b2); s4.w=f2bf(b3);
        *(short4*)&Bp[((kq>>3)*BN + n)*8 + (kq&7)] = s4;
      }
    }
    __syncthreads();
    #pragma unroll
    for (int ks = 0; ks < BK; ks += 32){
      const int kk = ks + quad*8;
      s8v af[MT], bfr[NT];
      #pragma unroll
      for (int mt=0; mt<MT; mt++)
        af[mt] = *(const s8v*)&Ap[((kk>>3)*BM + mbase + mt*16 + l16)*8];
      #pragma unroll
      for (int nt=0; nt<NT; nt++)
        bfr[nt] = *(const s8v*)&Bp[((kk>>3)*BN + nbase + nt*16 + l16)*8];
      #pragma unroll
      for (int mt=0; mt<MT; mt++)
        #pragma unroll
        for (int nt=0; nt<NT; nt++)
          acc[mt][nt] = __builtin_amdgcn_mfma_f32_16x16x32_bf16(af[mt], bfr[nt], acc[mt][nt], 0, 0, 0);
    }
    __syncthreads();
  }
  // ---- epilogue: C/D layout col=lane&15, row=quad*4+reg ----
  #pragma unroll
  for (int mt=0; mt<MT; mt++){
    #pragma unroll
    for (int nt=0; nt<NT; nt++){
      #pragma unroll
      for (int r=0; r<4; r++){
        int row = row0 + mbase + mt*16 + quad*4 + r;
        int cc  = col0 + nbase + nt*16 + l16;
        float v = acc[mt][nt][r];
        if (BIAS){ if (!ATOMIC || blockIdx.z==0) v += bias[cc]; }
        size_t idx = (size_t)row*ldc + cc;
        if (ATOMIC){
          atomicAdd(&C[idx], v);
          if (C2) atomicAdd(&C2[idx], v);
        } else {
          C[idx] = v;
          if (C2) C2[idx] = v;
        }
      }
    }
  }
}

// ---------------- virtual src_hidden row resolver ----------------
__device__ __forceinline__ const float* resolve_row(
    int b, int j, float& mval,
    const float* __restrict__ E_ctx, const int* __restrict__ context, const int* __restrict__ ctx_len,
    const float* __restrict__ pvh, const float* __restrict__ pv_mask,
    const float* __restrict__ tp_hidden, const int* __restrict__ tp_len,
    const float* __restrict__ ar_hidden, const int* __restrict__ ar_len)
{
  if (j < 512){ mval = (j < ctx_len[b]) ? 1.f : 0.f; return E_ctx + (size_t)context[b*LC_+j]*H_; }
  else if (j < 528){ int l=j-512; mval = pv_mask[b*LPV_+l]; return pvh + (size_t)(b*LPV_+l)*H_; }
  else if (j < 544){ int l=j-528; mval = (l < tp_len[b]) ? 1.f : 0.f; return tp_hidden + (size_t)(b*LTP_+l)*H_; }
  else { mval = (ar_len[b] > 0) ? 1.f : 0.f; return ar_hidden + (size_t)b*H_; }
}

// ---------------- flash-style single-pass attention chunk ----------------
// grid (64 batches, 8 chunks of 69 rows). Online softmax over the chunk; partial
// o (un-normalized), m, l written for the combine kernel.
__global__ __launch_bounds__(256) void attn_pass(
    const float* __restrict__ qk,
    const float* __restrict__ E_ctx, const int* __restrict__ context, const int* __restrict__ ctx_len,
    const float* __restrict__ pvh, const float* __restrict__ pv_mask,
    const float* __restrict__ tp_hidden, const int* __restrict__ tp_len,
    const float* __restrict__ ar_hidden, const int* __restrict__ ar_len,
    float* __restrict__ part_o, float* __restrict__ part_ml)
{
  const int b = blockIdx.x, c = blockIdx.y, t = threadIdx.x;
  __shared__ __align__(16) float rows[8][1024];
  __shared__ __align__(16) float4 qlds[256];
  __shared__ const float* rptr[8];
  __shared__ float rm[8], sp[8];
  qlds[t] = ((const float4*)(qk + (size_t)b*H_))[t];
  const int j0 = c*69;
  const int jn = (S_ - j0 < 69) ? (S_ - j0) : 69;
  const int w = t>>6, lane = t&63;
  float mcur = -3.4e38f, lsum = 0.f;
  float4 o = {0.f,0.f,0.f,0.f};
  for (int tt=0; tt<9; tt++){
    __syncthreads();
    if (t < 8){
      int jv = tt*8 + t;
      float mval = 0.f; const float* rp = nullptr;
      if (jv < jn) rp = resolve_row(b, j0+jv, mval, E_ctx, context, ctx_len, pvh, pv_mask, tp_hidden, tp_len, ar_hidden, ar_len);
      rptr[t] = rp; rm[t] = mval;
    }
    __syncthreads();
    {
      int rr = t >> 5, cc = t & 31;
      if (rm[rr] != 0.f){
        const float4* src = (const float4*)rptr[rr];
        #pragma unroll
        for (int i=0;i<8;i++)
          ((float4*)rows[rr])[cc + 32*i] = src[cc + 32*i];
      }
    }
    __syncthreads();
    #pragma unroll
    for (int rr = w*2; rr < w*2+2; rr++){
      if (rm[rr] != 0.f){
        float acc = 0.f;
        #pragma unroll
        for (int i=0;i<4;i++){
          float4 rv = ((const float4*)rows[rr])[lane + 64*i];
          float4 qv = qlds[lane + 64*i];
          acc += rv.x*qv.x + rv.y*qv.y + rv.z*qv.z + rv.w*qv.w;
        }
        #pragma unroll
        for (int off=32; off; off>>=1) acc += __shfl_down(acc, off, 64);
        if (lane==0) sp[rr] = acc * INV32;
      } else if (lane==0) sp[rr] = -3.4e38f;
    }
    __syncthreads();
    float mnew = mcur;
    #pragma unroll
    for (int r=0;r<8;r++) if (rm[r]!=0.f) mnew = fmaxf(mnew, sp[r]);
    float alpha = expf(mcur - mnew);
    float p[8]; float psum = 0.f;
    #pragma unroll
    for (int r=0;r<8;r++){ p[r] = (rm[r]!=0.f) ? expf(sp[r]-mnew) : 0.f; psum += p[r]; }
    lsum = lsum*alpha + psum;
    o.x*=alpha; o.y*=alpha; o.z*=alpha; o.w*=alpha;
    #pragma unroll
    for (int r=0;r<8;r++){
      if (p[r] != 0.f){
        float4 rv = ((const float4*)rows[r])[t];
        o.x += p[r]*rv.x; o.y += p[r]*rv.y; o.z += p[r]*rv.z; o.w += p[r]*rv.w;
      }
    }
    mcur = mnew;
  }
  ((float4*)(part_o + ((size_t)(b*8 + c))*1024))[t] = o;
  if (t==0){ part_ml[(b*8+c)*2] = mcur; part_ml[(b*8+c)*2+1] = lsum; }
}

__global__ __launch_bounds__(256) void attn_combine(
    const float* __restrict__ part_o, const float* __restrict__ part_ml,
    float* __restrict__ asrc)
{
  const int b = blockIdx.x, t = threadIdx.x;
  __shared__ float sm[8], sl[8];
  if (t < 8){ sm[t] = part_ml[(b*8+t)*2]; sl[t] = part_ml[(b*8+t)*2+1]; }
  __syncthreads();
  float M = -3.4e38f;
  #pragma unroll
  for (int i=0;i<8;i++) M = fmaxf(M, sm[i]);
  float wgt[8]; float Z = 0.f;
  #pragma unroll
  for (int i=0;i<8;i++){ wgt[i] = expf(sm[i]-M); Z += wgt[i]*sl[i]; }
  float4 o = {0.f,0.f,0.f,0.f};
  #pragma unroll
  for (int i=0;i<8;i++){
    float4 p = ((const float4*)(part_o + ((size_t)(b*8+i))*1024))[t];
    o.x += wgt[i]*p.x; o.y += wgt[i]*p.y; o.z += wgt[i]*p.z; o.w += wgt[i]*p.w;
  }
  float inv = 1.f / Z;
  o.x*=inv; o.y*=inv; o.z*=inv; o.w*=inv;
  ((float4*)(asrc + (size_t)b*H_))[t] = o;
}

// ---------------- copy logits: parallel dot pass, grid (64, 8 chunks of 68) ----------------
__global__ __launch_bounds__(256) void copy_score(
    const float* __restrict__ decr,
    const float* __restrict__ E_ctx, const int* __restrict__ context, const int* __restrict__ ctx_len,
    const float* __restrict__ pvh, const float* __restrict__ pv_mask,
    const float* __restrict__ tp_hidden, const int* __restrict__ tp_len,
    const float* __restrict__ ar_hidden, const int* __restrict__ ar_len,
    float* __restrict__ cl)
{
  const int b = blockIdx.x, c = blockIdx.y, t = threadIdx.x;
  __shared__ __align__(16) float4 dlds[256];
  {
    float4 d = ((const float4*)(decr + (size_t)b*H_))[t];
    d.x = tanhf(d.x); d.y = tanhf(d.y); d.z = tanhf(d.z); d.w = tanhf(d.w);
    dlds[t] = d;
  }
  __syncthreads();
  const int w = t>>6, lane = t&63;
  for (int i=0;i<17;i++){
    int j = c*68 + w*17 + i;
    float mval;
    const float* row = resolve_row(b, j, mval, E_ctx, context, ctx_len, pvh, pv_mask, tp_hidden, tp_len, ar_hidden, ar_len);
    float s;
    if (mval != 0.f){
      const float4* r4 = (const float4*)row;
      float acc = 0.f;
      #pragma unroll
      for (int k=0;k<4;k++){
        float4 a = r4[lane + 64*k]; float4 q = dlds[lane + 64*k];
        acc += a.x*q.x + a.y*q.y + a.z*q.z + a.w*q.w;
      }
      #pragma unroll
      for (int off=32; off; off>>=1) acc += __shfl_down(acc, off, 64);
      s = acc * INV32;
    } else s = NEGV * INV32;
    if (lane == 0) cl[b*544 + j] = s;
  }
}

// ---------------- global softmax stats over 8192 gen + 544 copy logits ----------------
__global__ __launch_bounds__(256) void copy_mz(
    const float* __restrict__ gen, const float* __restrict__ cl, float* __restrict__ mz)
{
  const int b = blockIdx.x, t = threadIdx.x;
  __shared__ float red[4];
  const int w = t>>6, lane = t&63;
  float gv[32];
  float lm = -3.4e38f;
  const float4* g4 = (const float4*)(gen + (size_t)b*V_);
  #pragma unroll
  for (int i=0;i<8;i++){
    float4 g = g4[t + 256*i];
    gv[4*i+0]=g.x*INV32; gv[4*i+1]=g.y*INV32; gv[4*i+2]=g.z*INV32; gv[4*i+3]=g.w*INV32;
    lm = fmaxf(lm, fmaxf(fmaxf(gv[4*i],gv[4*i+1]), fmaxf(gv[4*i+2],gv[4*i+3])));
  }
  for (int j = t; j < 544; j += 256) lm = fmaxf(lm, cl[b*544 + j]);
  #pragma unroll
  for (int off=32; off; off>>=1) lm = fmaxf(lm, __shfl_down(lm, off, 64));
  if (lane==0) red[w] = lm;
  __syncthreads();
  const float m = fmaxf(fmaxf(red[0],red[1]), fmaxf(red[2],red[3]));
  __syncthreads();
  float ls = 0.f;
  #pragma unroll
  for (int i=0;i<32;i++) ls += expf(gv[i] - m);
  for (int j = t; j < 544; j += 256) ls += expf(cl[b*544 + j] - m);
  #pragma unroll
  for (int off=32; off; off>>=1) ls += __shfl_down(ls, off, 64);
  if (lane==0) red[w] = ls;
  __syncthreads();
  if (t == 0){ mz[2*b] = m; mz[2*b+1] = red[0]+red[1]+red[2]+red[3]; }
}

// ---------------- p = gen_prob + copy_pv_p (dense part), write out0 ----------------
__global__ __launch_bounds__(256) void pbuild_kernel(
    const float* __restrict__ gen, const float* __restrict__ cl, const float* __restrict__ mz,
    const float* __restrict__ pv_m, float* __restrict__ out0, int step)
{
  const int b = blockIdx.x, ch = blockIdx.y, t = threadIdx.x;
  __shared__ float pvp[16];
  const float m = mz[2*b], Z = mz[2*b+1];
  if (t < 16) pvp[t] = expf(cl[b*544 + 512 + t] - m) / Z;
  __syncthreads();
  const int f4i = ch*256 + t;
  float4 g = ((const float4*)(gen + (size_t)b*V_))[f4i];
  float4 pb;
  pb.x = expf(g.x*INV32 - m)/Z;
  pb.y = expf(g.y*INV32 - m)/Z;
  pb.z = expf(g.z*INV32 - m)/Z;
  pb.w = expf(g.w*INV32 - m)/Z;
  #pragma unroll
  for (int l=0;l<16;l++){
    float wgt = pvp[l];
    float4 q = ((const float4*)(pv_m + (size_t)(b*LPV_+l)*V_))[f4i];
    pb.x += wgt*q.x; pb.y += wgt*q.y; pb.z += wgt*q.z; pb.w += wgt*q.w;
  }
  ((float4*)(out0 + (size_t)(b*PREF_+step)*V_))[f4i] = pb;
}

// ---------------- scatter: ccopy (ctx via glo2loc) + copy_tp ----------------
__global__ __launch_bounds__(256) void scatter_kernel(
    const float* __restrict__ cl, const float* __restrict__ mz,
    const int* __restrict__ context, const int* __restrict__ glo2loc, const int* __restrict__ tp_path,
    float* __restrict__ out0, int step)
{
  const int b = blockIdx.x, t = threadIdx.x;
  const float m = mz[2*b], Z = mz[2*b+1];
  float* dst = out0 + (size_t)(b*PREF_+step)*V_;
  for (int jj = t; jj < 528; jj += 256){
    float val; int tgt;
    if (jj < 512){
      val = expf(cl[b*544 + jj] - m) / Z;
      tgt = glo2loc[context[b*LC_ + jj]];
    } else {
      int l = jj - 512;
      val = expf(cl[b*544 + 528 + l] - m) / Z;
      tgt = tp_path[b*LTP_ + l];
    }
    if (val != 0.f) atomicAdd(dst + tgt, val);
  }
}

// ---------------- gumbel-softmax sampling (JAX threefry, partitionable XOR-fold) ----------------
__global__ __launch_bounds__(256) void sample_kernel(
    const float* __restrict__ out0, float* __restrict__ out1, int step)
{
  const int b = blockIdx.x, t = threadIdx.x;
  __shared__ float red[4];
  uint32_t kx = 0u, ky = (uint32_t)step;
  tf2x32(0u, 42u, kx, ky);
  const float* p = out0 + (size_t)(b*PREF_ + step)*V_;
  float lv[32];
  float lm = -3.4e38f;
  #pragma unroll
  for (int i=0;i<32;i++){
    int v = t + 256*i;
    float pv = p[v];
    uint32_t j = (uint32_t)(b*V_ + v);
    uint32_t x0 = 0u, x1 = j;
    tf2x32(kx, ky, x0, x1);
    uint32_t bits = x0 ^ x1;
    float f = __uint_as_float((bits >> 9) | 0x3F800000u) - 1.0f;
    float u = fmaxf(1e-10f, f + 1e-10f);
    float g = -logf(-logf(u));
    float l = (logf(pv + 1e-10f) + g) / 0.67f;
    lv[i] = l;
    lm = fmaxf(lm, l);
  }
  const int w = t>>6, lane = t&63;
  #pragma unroll
  for (int off=32; off; off>>=1) lm = fmaxf(lm, __shfl_down(lm, off, 64));
  if (lane==0) red[w] = lm;
  __syncthreads();
  const float m = fmaxf(fmaxf(red[0],red[1]), fmaxf(red[2],red[3]));
  __syncthreads();
  float ls = 0.f;
  #pragma unroll
  for (int i=0;i<32;i++){ lv[i] = expf(lv[i] - m); ls += lv[i]; }
  #pragma unroll
  for (int off=32; off; off>>=1) ls += __shfl_down(ls, off, 64);
  if (lane==0) red[w] = ls;
  __syncthreads();
  const float Z = red[0]+red[1]+red[2]+red[3];
  float* y = out1 + (size_t)(b*PREF_ + step)*V_;
  #pragma unroll
  for (int i=0;i<32;i++) y[t + 256*i] = lv[i] / Z;
}

// ---------------- host ----------------
extern "C" void kernel_launch(void* const* d_in, const int* in_sizes, int n_in,
                              void* d_out, int out_size, void* d_ws, size_t ws_size,
                              hipStream_t stream)
{
  (void)in_sizes; (void)n_in; (void)out_size; (void)ws_size;
  const int*   context   = (const int*)  d_in[0];
  const int*   ctx_len   = (const int*)  d_in[1];
  const float* pv_m      = (const float*)d_in[2];
  const float* pv_mask   = (const float*)d_in[3];
  const int*   ar_len    = (const int*)  d_in[5];
  const int*   tp_path   = (const int*)  d_in[6];
  const int*   tp_len    = (const int*)  d_in[7];
  const float* tp_hidden = (const float*)d_in[8];
  const float* ar_hidden = (const float*)d_in[9];
  const float* E_ctx     = (const float*)d_in[10];
  const float* W_p       = (const float*)d_in[11];
  const float* E_topic   = (const float*)d_in[12];
  const float* W_q       = (const float*)d_in[13];
  const float* W_k       = (const float*)d_in[14];
  const float* W_v       = (const float*)d_in[15];
  const float* W_o       = (const float*)d_in[16];
  const float* gen_W     = (const float*)d_in[17];
  const float* gen_b     = (const float*)d_in[18];
  const int*   glo2loc   = (const int*)  d_in[19];

  float* out0 = (float*)d_out;
  float* out1 = out0 + (size_t)B_*PREF_*V_;

  float* ws      = (float*)d_ws;
  float* Mw      = ws;  ws += 1024*1024;     // W_q @ W_k^T
  float* pvh     = ws;  ws += 1024*1024;     // pv_hidden (B*LPV x H)
  float* y0      = ws;  ws += (size_t)B_*V_; // one-hot BOS
  float* emb     = ws;  ws += B_*H_;         // -- per-step zero region start --
  float* qk      = ws;  ws += B_*H_;
  float* t1      = ws;  ws += B_*H_;
  float* decr    = ws;  ws += B_*H_;         // -- per-step zero region end --
  float* gen     = ws;  ws += (size_t)B_*V_;
  float* asrc    = ws;  ws += B_*H_;
  float* cl      = ws;  ws += B_*544;
  float* mz      = ws;  ws += 2*B_;
  float* part_o  = ws;  ws += (size_t)B_*8*H_;
  float* part_ml = ws;  ws += B_*8*2;
  const size_t zbytes = (size_t)(4*B_*H_) * sizeof(float);

  // ---- one-time setup ----
  init_y0<<<dim3(2048), dim3(256), 0, stream>>>(y0);
  hipMemsetAsync(pvh, 0, (size_t)1024*1024*sizeof(float), stream);
  // M = W_q @ W_k^T   (TRANSB; M=N=K=1024)
  mgemm<128,true,false,false,false><<<dim3(8,8,1), dim3(256), 0, stream>>>(
      W_q, H_, W_k, H_, Mw, (float*)nullptr, H_, 1024, nullptr);
  // pv_hidden = pv_m @ W_p  (M=1024, K=8192, N=1024; split-K z=4)
  mgemm<128,false,true,false,false><<<dim3(8,8,4), dim3(256), 0, stream>>>(
      pv_m, V_, W_p, H_, pvh, (float*)nullptr, H_, 2048, nullptr);

  // ---- decode loop ----
  for (int t = 0; t < PREF_; ++t){
    hipMemsetAsync(emb, 0, zbytes, stream);
    const float* yprev = (t == 0) ? y0 : (out1 + (size_t)(t-1)*V_);
    const int    ylda  = (t == 0) ? V_ : PREF_*V_;
    // emb = y_prev @ E_topic (dual-write t1 = emb); M=64,K=8192,N=1024, z=16
    mgemm<64,false,true,false,false><<<dim3(8,1,16), dim3(256), 0, stream>>>(
        yprev, ylda, E_topic, H_, emb, t1, H_, 512, nullptr);
    // qk = emb @ Mw ; z=8
    mgemm<64,false,true,false,false><<<dim3(8,1,8), dim3(256), 0, stream>>>(
        emb, H_, Mw, H_, qk, (float*)nullptr, H_, 128, nullptr);
    // attention (flash single pass + combine) -> asrc
    attn_pass<<<dim3(64,8), dim3(256), 0, stream>>>(
        qk, E_ctx, context, ctx_len, pvh, pv_mask, tp_hidden, tp_len, ar_hidden, ar_len, part_o, part_ml);
    attn_combine<<<dim3(64), dim3(256), 0, stream>>>(part_o, part_ml, asrc);
    // t1 += asrc @ W_v
    mgemm<64,false,true,false,false><<<dim3(8,1,8), dim3(256), 0, stream>>>(
        asrc, H_, W_v, H_, t1, (float*)nullptr, H_, 128, nullptr);
    // decr = t1 @ W_o
    mgemm<64,false,true,false,false><<<dim3(8,1,8), dim3(256), 0, stream>>>(
        t1, H_, W_o, H_, decr, (float*)nullptr, H_, 128, nullptr);
    // gen = tanh(decr) @ gen_W + gen_b   (M=64,K=1024,N=8192, direct store)
    mgemm<64,false,false,true,true><<<dim3(64,1,1), dim3(256), 0, stream>>>(
        decr, H_, gen_W, V_, gen, (float*)nullptr, V_, 1024, gen_b);
    // copy logits (parallel dot) + softmax stats
    copy_score<<<dim3(64,8), dim3(256), 0, stream>>>(
        decr, E_ctx, context, ctx_len, pvh, pv_mask, tp_hidden, tp_len, ar_hidden, ar_len, cl);
    copy_mz<<<dim3(64), dim3(256), 0, stream>>>(gen, cl, mz);
    // dense p -> out0
    pbuild_kernel<<<dim3(64,8), dim3(256), 0, stream>>>(gen, cl, mz, pv_m, out0, t);
    // scatter ctx/tp copy mass
    scatter_kernel<<<dim3(64), dim3(256), 0, stream>>>(cl, mz, context, glo2loc, tp_path, out0, t);
    // gumbel-softmax sample -> out1
    sample_kernel<<<dim3(64), dim3(256), 0, stream>>>(out0, out1, t);
  }
}

// Round 5
// 3341.529 us; speedup vs baseline: 2.9428x; 1.1824x over previous
//
#include <hip/hip_runtime.h>
#include <hip/hip_bf16.h>
#include <stdint.h>

#define B_    64
#define LC_   512
#define V_    8192
#define H_    1024
#define PREF_ 16
#define S_    545
#define SP_   560          // padded src rows (545 -> 560 = 35*16)
#define KA_   9216         // Abuf row length: 8192 (y) + 1024 (asrc)
#define NEGV  (-1e9f)
#define INV32 0.03125f     // H^-0.5

typedef __attribute__((ext_vector_type(8))) short s8v;   // 8 bf16 MFMA frag
typedef __attribute__((ext_vector_type(4))) float f4a;   // MFMA C/D frag

__device__ __forceinline__ short f2bf(float f){
  uint32_t u = __float_as_uint(f);
  uint32_t r = (u + 0x7fffu + ((u >> 16) & 1u)) >> 16;
  return (short)(r & 0xffffu);
}
__device__ __forceinline__ float bf2f(short s){
  return __uint_as_float(((uint32_t)(uint16_t)s) << 16);
}

// ---------------- threefry2x32 (exact JAX semantics) ----------------
__device__ __forceinline__ uint32_t rotl32(uint32_t x, uint32_t d){ return (x<<d)|(x>>(32u-d)); }
__device__ __forceinline__ void tf2x32(uint32_t k0, uint32_t k1, uint32_t& x0, uint32_t& x1){
  uint32_t ks0=k0, ks1=k1, ks2=k0^k1^0x1BD11BDAu;
  x0+=ks0; x1+=ks1;
  x0+=x1; x1=rotl32(x1,13); x1^=x0;
  x0+=x1; x1=rotl32(x1,15); x1^=x0;
  x0+=x1; x1=rotl32(x1,26); x1^=x0;
  x0+=x1; x1=rotl32(x1, 6); x1^=x0;
  x0+=ks1; x1+=ks2+1u;
  x0+=x1; x1=rotl32(x1,17); x1^=x0;
  x0+=x1; x1=rotl32(x1,29); x1^=x0;
  x0+=x1; x1=rotl32(x1,16); x1^=x0;
  x0+=x1; x1=rotl32(x1,24); x1^=x0;
  x0+=ks2; x1+=ks0+2u;
  x0+=x1; x1=rotl32(x1,13); x1^=x0;
  x0+=x1; x1=rotl32(x1,15); x1^=x0;
  x0+=x1; x1=rotl32(x1,26); x1^=x0;
  x0+=x1; x1=rotl32(x1, 6); x1^=x0;
  x0+=ks0; x1+=ks1+3u;
  x0+=x1; x1=rotl32(x1,17); x1^=x0;
  x0+=x1; x1=rotl32(x1,29); x1^=x0;
  x0+=x1; x1=rotl32(x1,16); x1^=x0;
  x0+=x1; x1=rotl32(x1,24); x1^=x0;
  x0+=ks1; x1+=ks2+4u;
  x0+=x1; x1=rotl32(x1,13); x1^=x0;
  x0+=x1; x1=rotl32(x1,15); x1^=x0;
  x0+=x1; x1=rotl32(x1,26); x1^=x0;
  x0+=x1; x1=rotl32(x1, 6); x1^=x0;
  x0+=ks2; x1+=ks0+5u;
}

// ---------------- casts ----------------
__global__ __launch_bounds__(256) void cast_bf(const float* __restrict__ in, short* __restrict__ out){
  size_t idx = ((size_t)blockIdx.x*256 + threadIdx.x)*4;
  float4 v = *(const float4*)(in+idx);
  short4 s; s.x=f2bf(v.x); s.y=f2bf(v.y); s.z=f2bf(v.z); s.w=f2bf(v.w);
  *(short4*)(out+idx) = s;
}
// fp32 [K][N] -> k-packeted bf16: off(k,n) = ((k>>3)*N + n)*8 + (k&7)
__global__ __launch_bounds__(256) void cast_pack(const float* __restrict__ in, short* __restrict__ out, int N){
  int gid = blockIdx.x*256 + threadIdx.x;
  int k = gid / (N>>2);
  int n = (gid % (N>>2))*4;
  float4 v = *(const float4*)(in + (size_t)k*N + n);
  size_t base = ((size_t)(k>>3)*N + n)*8 + (k&7);
  out[base] = f2bf(v.x); out[base+8] = f2bf(v.y); out[base+16] = f2bf(v.z); out[base+24] = f2bf(v.w);
}

// ---------------- bf16-in GEMM: A row-major bf16 (direct-global frags), B k-packeted bf16 ----------------
template<int BM, bool ATOMIC, bool BIAS>
__global__ __launch_bounds__(256) void bgemm(
    const short* __restrict__ A, int lda,
    const short* __restrict__ Bp, int ldn,
    float* __restrict__ C, int ldc,
    int kchunk, const float* __restrict__ bias)
{
  constexpr int BN = 128, BK = 64;
  __shared__ short Bl[BK*BN];
  const int t = threadIdx.x;
  const int w = t >> 6, lane = t & 63;
  const int quad = lane >> 4, l16 = lane & 15;
  const int col0 = blockIdx.x * BN;
  const int row0 = (BM==128) ? blockIdx.y * BM : 0;
  const int k0 = blockIdx.z * kchunk, kend = k0 + kchunk;
  constexpr int MT = 2;
  constexpr int NT = (BM==128) ? 8 : 4;
  const int mbase = (BM==128) ? w*32 : (w&1)*32;
  const int nbase = (BM==128) ? 0 : (w>>1)*64;
  f4a acc[MT][NT];
  #pragma unroll
  for (int mt=0; mt<MT; mt++)
    #pragma unroll
    for (int nt=0; nt<NT; nt++)
      acc[mt][nt] = (f4a){0.f,0.f,0.f,0.f};

  for (int kb = k0; kb < kend; kb += BK){
    #pragma unroll
    for (int i=0;i<4;i++){                      // stage B tile: 1024 short8
      int idx = t + i*256;
      int p = idx >> 7, n = idx & 127;
      ((s8v*)Bl)[idx] = *(const s8v*)(Bp + (((size_t)((kb>>3)+p))*ldn + col0 + n)*8);
    }
    __syncthreads();
    #pragma unroll
    for (int ks=0; ks<BK; ks+=32){
      const int kk = kb + ks + quad*8;
      const int kl = ks + quad*8;
      s8v af[MT], bfr[NT];
      #pragma unroll
      for (int mt=0; mt<MT; mt++)
        af[mt] = *(const s8v*)(A + (size_t)(row0+mbase+mt*16+l16)*lda + kk);
      #pragma unroll
      for (int nt=0; nt<NT; nt++)
        bfr[nt] = *(const s8v*)&Bl[((kl>>3)*BN + nbase + nt*16 + l16)*8];
      #pragma unroll
      for (int mt=0; mt<MT; mt++)
        #pragma unroll
        for (int nt=0; nt<NT; nt++)
          acc[mt][nt] = __builtin_amdgcn_mfma_f32_16x16x32_bf16(af[mt], bfr[nt], acc[mt][nt], 0, 0, 0);
    }
    __syncthreads();
  }
  #pragma unroll
  for (int mt=0; mt<MT; mt++){
    #pragma unroll
    for (int nt=0; nt<NT; nt++){
      #pragma unroll
      for (int r=0; r<4; r++){
        int row = row0 + mbase + mt*16 + quad*4 + r;
        int cc  = col0 + nbase + nt*16 + l16;
        float v = acc[mt][nt][r];
        if (BIAS){ if (!ATOMIC || blockIdx.z==0) v += bias[cc]; }
        size_t idx = (size_t)row*ldc + cc;
        if (ATOMIC) atomicAdd(&C[idx], v);
        else        C[idx] = v;
      }
    }
  }
}

// ---------------- fp32-in GEMM (setup only), BM=128; PACK: bf16 k-packeted output ----------------
template<bool TRANSB, bool PACK>
__global__ __launch_bounds__(256) void mgemm(
    const float* __restrict__ A, int lda,
    const float* __restrict__ Bm, int ldb,
    float* __restrict__ C, int ldc, int K)
{
  constexpr int BM = 128, BN = 128, BK = 64;
  __shared__ short Ap[BK*BM];
  __shared__ short Bp[BK*BN];
  const int t = threadIdx.x;
  const int w = t >> 6, lane = t & 63;
  const int quad = lane >> 4, l16 = lane & 15;
  const int col0 = blockIdx.x * BN;
  const int row0 = blockIdx.y * BM;
  constexpr int MT = 2, NT = 8;
  const int mbase = w*32, nbase = 0;
  f4a acc[MT][NT];
  #pragma unroll
  for (int mt=0; mt<MT; mt++)
    #pragma unroll
    for (int nt=0; nt<NT; nt++)
      acc[mt][nt] = (f4a){0.f,0.f,0.f,0.f};

  for (int kb = 0; kb < K; kb += BK){
    #pragma unroll
    for (int i = 0; i < 8; ++i){
      int idx = t + i*256;
      int m = idx >> 4, kq = (idx & 15) * 4;
      float4 a = *(const float4*)(A + (size_t)(row0+m)*lda + kb + kq);
      short4 s4; s4.x=f2bf(a.x); s4.y=f2bf(a.y); s4.z=f2bf(a.z); s4.w=f2bf(a.w);
      *(short4*)&Ap[((kq>>3)*BM + m)*8 + (kq&7)] = s4;
    }
    if (TRANSB){
      #pragma unroll
      for (int i = 0; i < 8; ++i){
        int idx = t + i*256;
        int n = idx >> 4, kq = (idx & 15) * 4;
        float4 bv = *(const float4*)(Bm + (size_t)(col0+n)*ldb + kb + kq);
        short4 s4; s4.x=f2bf(bv.x); s4.y=f2bf(bv.y); s4.z=f2bf(bv.z); s4.w=f2bf(bv.w);
        *(short4*)&Bp[((kq>>3)*BN + n)*8 + (kq&7)] = s4;
      }
    } else {
      #pragma unroll
      for (int c = 0; c < 8; ++c){
        int idx = t + c*256;
        int n = idx & 127, kq = (idx >> 7) * 4;
        const float* bp0 = Bm + (size_t)(kb+kq)*ldb + col0 + n;
        float b0 = bp0[0], b1 = bp0[ldb], b2 = bp0[2*(size_t)ldb], b3 = bp0[3*(size_t)ldb];
        short4 s4; s4.x=f2bf(b0); s4.y=f2bf(b1); s4.z=f2bf(b2); s4.w=f2bf(b3);
        *(short4*)&Bp[((kq>>3)*BN + n)*8 + (kq&7)] = s4;
      }
    }
    __syncthreads();
    #pragma unroll
    for (int ks = 0; ks < BK; ks += 32){
      const int kk = ks + quad*8;
      s8v af[MT], bfr[NT];
      #pragma unroll
      for (int mt=0; mt<MT; mt++)
        af[mt] = *(const s8v*)&Ap[((kk>>3)*BM + mbase + mt*16 + l16)*8];
      #pragma unroll
      for (int nt=0; nt<NT; nt++)
        bfr[nt] = *(const s8v*)&Bp[((kk>>3)*BN + nbase + nt*16 + l16)*8];
      #pragma unroll
      for (int mt=0; mt<MT; mt++)
        #pragma unroll
        for (int nt=0; nt<NT; nt++)
          acc[mt][nt] = __builtin_amdgcn_mfma_f32_16x16x32_bf16(af[mt], bfr[nt], acc[mt][nt], 0, 0, 0);
    }
    __syncthreads();
  }
  #pragma unroll
  for (int mt=0; mt<MT; mt++){
    #pragma unroll
    for (int nt=0; nt<NT; nt++){
      #pragma unroll
      for (int r=0; r<4; r++){
        int row = row0 + mbase + mt*16 + quad*4 + r;
        int cc  = col0 + nbase + nt*16 + l16;
        float v = acc[mt][nt][r];
        if (PACK){
          size_t off = (((size_t)(row>>3))*ldc + cc)*8 + (row&7);
          ((short*)C)[off] = f2bf(v);
        } else {
          C[(size_t)row*ldc + cc] = v;
        }
      }
    }
  }
}

// ---------------- src_hidden materialization (bf16) + mask ----------------
__global__ __launch_bounds__(256) void src_build(
    const float* __restrict__ E_ctx, const int* __restrict__ context, const int* __restrict__ ctx_len,
    const float* __restrict__ pvh, const float* __restrict__ pv_mask,
    const float* __restrict__ tp_hidden, const int* __restrict__ tp_len,
    const float* __restrict__ ar_hidden, const int* __restrict__ ar_len,
    short* __restrict__ src, float* __restrict__ smask)
{
  const int b = blockIdx.x, jg = blockIdx.y, t = threadIdx.x;
  const int r = t >> 4, c0 = (t & 15) * 64;
  const int j = jg*16 + r;
  const float* srcp = nullptr;
  float msk = 0.f;
  if (j < 512){
    int idx = context[b*LC_ + j];
    bool on = j < ctx_len[b];
    msk = on ? 1.f : 0.f;
    srcp = on ? (E_ctx + (size_t)idx*H_) : nullptr;   // ref zeroes masked ctx rows
  } else if (j < 528){
    srcp = pvh + (size_t)(b*16 + j-512)*H_;
    msk = pv_mask[b*16 + j-512];
  } else if (j < 544){
    srcp = tp_hidden + (size_t)(b*16 + j-528)*H_;
    msk = ((j-528) < tp_len[b]) ? 1.f : 0.f;
  } else if (j == 544){
    srcp = ar_hidden + (size_t)b*H_;
    msk = (ar_len[b] > 0) ? 1.f : 0.f;
  }
  short* dst = src + (size_t)(b*SP_ + j)*H_ + c0;
  if (srcp){
    #pragma unroll 4
    for (int i=0;i<16;i++){
      float4 v = *(const float4*)(srcp + c0 + i*4);
      short4 s; s.x=f2bf(v.x); s.y=f2bf(v.y); s.z=f2bf(v.z); s.w=f2bf(v.w);
      *(short4*)(dst + i*4) = s;
    }
  } else {
    short4 z = {0,0,0,0};
    #pragma unroll 4
    for (int i=0;i<16;i++) *(short4*)(dst + i*4) = z;
  }
  if ((t & 15) == 0) smask[b*SP_ + j] = msk;
}

__global__ __launch_bounds__(256) void abuf_init(short* __restrict__ Abuf){
  int v = blockIdx.x*256 + threadIdx.x;  // grid (36, 64)
  int b = blockIdx.y;
  Abuf[(size_t)b*KA_ + v] = (v == 2) ? (short)0x3F80 : (short)0;
}

// ---------------- attention: flash chunk pass over bf16 src ----------------
__global__ __launch_bounds__(256) void attn_pass(
    const float* __restrict__ qk, const short* __restrict__ src, const float* __restrict__ smask,
    float* __restrict__ part_o, float* __restrict__ part_ml)
{
  const int b = blockIdx.x, c = blockIdx.y, t = threadIdx.x;
  const int w = t>>6, lane = t&63;
  __shared__ float sv[70], pr[70], red[4];
  float qreg[16];
  {
    const float4* q4 = (const float4*)(qk + (size_t)b*H_ + lane*16);
    #pragma unroll
    for (int i=0;i<4;i++){ float4 v = q4[i]; qreg[4*i]=v.x; qreg[4*i+1]=v.y; qreg[4*i+2]=v.z; qreg[4*i+3]=v.w; }
  }
  const int j0 = c*70;
  for (int r = w; r < 70; r += 4){
    float msk = smask[b*SP_ + j0 + r];
    float s = -3.4e38f;
    if (msk != 0.f){
      const s8v* rp = (const s8v*)(src + (size_t)(b*SP_ + j0 + r)*H_);
      s8v v0 = rp[lane*2], v1 = rp[lane*2+1];
      float acc = 0.f;
      #pragma unroll
      for (int i=0;i<8;i++) acc += bf2f(v0[i])*qreg[i];
      #pragma unroll
      for (int i=0;i<8;i++) acc += bf2f(v1[i])*qreg[8+i];
      #pragma unroll
      for (int off=32; off; off>>=1) acc += __shfl_down(acc, off, 64);
      s = acc * INV32;
    }
    if (lane == 0) sv[r] = s;
  }
  __syncthreads();
  float lm = (t < 70) ? sv[t] : -3.4e38f;
  #pragma unroll
  for (int off=32; off; off>>=1) lm = fmaxf(lm, __shfl_down(lm, off, 64));
  if (lane==0) red[w] = lm;
  __syncthreads();
  const float m = fmaxf(fmaxf(red[0],red[1]), fmaxf(red[2],red[3]));
  __syncthreads();
  if (t < 70) pr[t] = (sv[t] > -1e37f) ? expf(sv[t]-m) : 0.f;
  __syncthreads();
  float ls = (t < 70) ? pr[t] : 0.f;
  #pragma unroll
  for (int off=32; off; off>>=1) ls += __shfl_down(ls, off, 64);
  if (lane==0) red[w] = ls;
  __syncthreads();
  const float lsum = red[0]+red[1]+red[2]+red[3];
  float4 o = {0.f,0.f,0.f,0.f};
  const short* base = src + (size_t)(b*SP_ + j0)*H_ + t*4;
  for (int r=0;r<70;r++){
    float p_ = pr[r];
    if (p_ != 0.f){
      short4 s4 = *(const short4*)(base + (size_t)r*H_);
      o.x += p_*bf2f(s4.x); o.y += p_*bf2f(s4.y); o.z += p_*bf2f(s4.z); o.w += p_*bf2f(s4.w);
    }
  }
  ((float4*)(part_o + (size_t)(b*8+c)*H_))[t] = o;
  if (t==0){ part_ml[(b*8+c)*2] = m; part_ml[(b*8+c)*2+1] = lsum; }
}

// combine chunks -> asrc, written as bf16 into Abuf cols [8192..9215]
__global__ __launch_bounds__(256) void attn_combine(
    const float* __restrict__ part_o, const float* __restrict__ part_ml,
    short* __restrict__ Abuf)
{
  const int b = blockIdx.x, t = threadIdx.x;
  __shared__ float sm[8], sl[8];
  if (t < 8){ sm[t] = part_ml[(b*8+t)*2]; sl[t] = part_ml[(b*8+t)*2+1]; }
  __syncthreads();
  float M = -3.4e38f;
  #pragma unroll
  for (int i=0;i<8;i++) M = fmaxf(M, sm[i]);
  float wgt[8]; float Z = 0.f;
  #pragma unroll
  for (int i=0;i<8;i++){ wgt[i] = expf(sm[i]-M); Z += wgt[i]*sl[i]; }
  float4 o = {0.f,0.f,0.f,0.f};
  #pragma unroll
  for (int i=0;i<8;i++){
    float4 p = ((const float4*)(part_o + (size_t)(b*8+i)*H_))[t];
    o.x += wgt[i]*p.x; o.y += wgt[i]*p.y; o.z += wgt[i]*p.z; o.w += wgt[i]*p.w;
  }
  float inv = 1.f / Z;
  short4 s4; s4.x=f2bf(o.x*inv); s4.y=f2bf(o.y*inv); s4.z=f2bf(o.z*inv); s4.w=f2bf(o.w*inv);
  *(short4*)(Abuf + (size_t)b*KA_ + 8192 + t*4) = s4;
}

// dtan = bf16(tanh(decr))
__global__ __launch_bounds__(256) void tanhcast(const float* __restrict__ decr, short* __restrict__ dtan){
  int idx = blockIdx.x*256 + threadIdx.x;   // grid 64 -> 16384 float4
  float4 v = ((const float4*)decr)[idx];
  short4 s; s.x=f2bf(tanhf(v.x)); s.y=f2bf(tanhf(v.y)); s.z=f2bf(tanhf(v.z)); s.w=f2bf(tanhf(v.w));
  ((short4*)dtan)[idx] = s;
}

// ---------------- copy logits over bf16 src ----------------
__global__ __launch_bounds__(256) void copy_score(
    const short* __restrict__ dtan, const short* __restrict__ src, const float* __restrict__ smask,
    float* __restrict__ cl)
{
  const int b = blockIdx.x, c = blockIdx.y, t = threadIdx.x;
  const int w = t>>6, lane = t&63;
  float qd[16];
  {
    const s8v* d8 = (const s8v*)(dtan + (size_t)b*H_ + lane*16);
    s8v d0 = d8[0], d1 = d8[1];
    #pragma unroll
    for (int i=0;i<8;i++){ qd[i] = bf2f(d0[i]); qd[8+i] = bf2f(d1[i]); }
  }
  for (int r = w; r < 68; r += 4){
    int j = c*68 + r;
    float msk = smask[b*SP_ + j];
    float s;
    if (msk != 0.f){
      const s8v* rp = (const s8v*)(src + (size_t)(b*SP_ + j)*H_);
      s8v v0 = rp[lane*2], v1 = rp[lane*2+1];
      float acc = 0.f;
      #pragma unroll
      for (int i=0;i<8;i++) acc += bf2f(v0[i])*qd[i];
      #pragma unroll
      for (int i=0;i<8;i++) acc += bf2f(v1[i])*qd[8+i];
      #pragma unroll
      for (int off=32; off; off>>=1) acc += __shfl_down(acc, off, 64);
      s = acc * INV32;
    } else s = NEGV * INV32;
    if (lane == 0) cl[b*544 + j] = s;
  }
}

// ---------------- fused: softmax stats + p build + scatter + gumbel sample ----------------
__global__ __launch_bounds__(256) void fuse_out(
    const float* __restrict__ gen, const float* __restrict__ cl, const float* __restrict__ pv_m,
    const int* __restrict__ context, const int* __restrict__ glo2loc, const int* __restrict__ tp_path,
    float* __restrict__ out0, float* __restrict__ out1, short* __restrict__ Abuf, int step)
{
  const int b = blockIdx.x, t = threadIdx.x;
  const int w = t>>6, lane = t&63;
  __shared__ float pl[V_];
  __shared__ float red[4];
  __shared__ float pvp[16];
  float4 gv[8];
  const float4* g4 = (const float4*)(gen + (size_t)b*V_);
  float lm = -3.4e38f;
  #pragma unroll
  for (int i=0;i<8;i++){
    float4 g = g4[t + 256*i];
    g.x*=INV32; g.y*=INV32; g.z*=INV32; g.w*=INV32;
    gv[i] = g;
    lm = fmaxf(lm, fmaxf(fmaxf(g.x,g.y), fmaxf(g.z,g.w)));
  }
  for (int jj=t; jj<544; jj+=256) lm = fmaxf(lm, cl[b*544+jj]);
  #pragma unroll
  for (int off=32; off; off>>=1) lm = fmaxf(lm, __shfl_down(lm, off, 64));
  if (lane==0) red[w] = lm;
  __syncthreads();
  const float m = fmaxf(fmaxf(red[0],red[1]), fmaxf(red[2],red[3]));
  __syncthreads();
  float ls = 0.f;
  #pragma unroll
  for (int i=0;i<8;i++){
    gv[i].x = expf(gv[i].x - m); gv[i].y = expf(gv[i].y - m);
    gv[i].z = expf(gv[i].z - m); gv[i].w = expf(gv[i].w - m);
    ls += gv[i].x + gv[i].y + gv[i].z + gv[i].w;
  }
  for (int jj=t; jj<544; jj+=256) ls += expf(cl[b*544+jj] - m);
  #pragma unroll
  for (int off=32; off; off>>=1) ls += __shfl_down(ls, off, 64);
  if (lane==0) red[w] = ls;
  __syncthreads();
  const float Z = red[0]+red[1]+red[2]+red[3];
  const float invZ = 1.f / Z;
  if (t < 16) pvp[t] = expf(cl[b*544 + 512 + t] - m) * invZ;
  __syncthreads();
  #pragma unroll
  for (int i=0;i<8;i++){ gv[i].x*=invZ; gv[i].y*=invZ; gv[i].z*=invZ; gv[i].w*=invZ; }
  for (int l=0;l<16;l++){
    float wl = pvp[l];
    const float4* pv4 = (const float4*)(pv_m + (size_t)(b*16+l)*V_);
    #pragma unroll
    for (int i=0;i<8;i++){
      float4 q = pv4[t + 256*i];
      gv[i].x += wl*q.x; gv[i].y += wl*q.y; gv[i].z += wl*q.z; gv[i].w += wl*q.w;
    }
  }
  #pragma unroll
  for (int i=0;i<8;i++) ((float4*)pl)[t + 256*i] = gv[i];
  __syncthreads();
  for (int jj=t; jj<528; jj+=256){
    float val; int tgt;
    if (jj < 512){
      val = expf(cl[b*544 + jj] - m) * invZ;
      tgt = glo2loc[context[b*LC_ + jj]];
    } else {
      int l = jj - 512;
      val = expf(cl[b*544 + 528 + l] - m) * invZ;
      tgt = tp_path[b*16 + l];
    }
    if (val != 0.f) atomicAdd(&pl[tgt], val);
  }
  __syncthreads();
  // out0 + gumbel sample
  float* o0 = out0 + (size_t)(b*PREF_+step)*V_;
  uint32_t kx = 0u, ky = (uint32_t)step;
  tf2x32(0u, 42u, kx, ky);
  float lv[32];
  float lm2 = -3.4e38f;
  #pragma unroll
  for (int i=0;i<8;i++){
    float4 p4 = ((const float4*)pl)[t + 256*i];
    ((float4*)o0)[t + 256*i] = p4;
    float pe[4] = {p4.x, p4.y, p4.z, p4.w};
    #pragma unroll
    for (int k=0;k<4;k++){
      int v = 4*(t + 256*i) + k;
      uint32_t j = (uint32_t)(b*V_ + v);
      uint32_t x0 = 0u, x1 = j;
      tf2x32(kx, ky, x0, x1);
      uint32_t bits = x0 ^ x1;
      float f = __uint_as_float((bits >> 9) | 0x3F800000u) - 1.0f;
      float u = fmaxf(1e-10f, f + 1e-10f);
      float g = -logf(-logf(u));
      float l = (logf(pe[k] + 1e-10f) + g) / 0.67f;
      lv[4*i+k] = l;
      lm2 = fmaxf(lm2, l);
    }
  }
  #pragma unroll
  for (int off=32; off; off>>=1) lm2 = fmaxf(lm2, __shfl_down(lm2, off, 64));
  if (lane==0) red[w] = lm2;
  __syncthreads();
  const float m2 = fmaxf(fmaxf(red[0],red[1]), fmaxf(red[2],red[3]));
  __syncthreads();
  float ls2 = 0.f;
  #pragma unroll
  for (int i=0;i<32;i++){ lv[i] = expf(lv[i] - m2); ls2 += lv[i]; }
  #pragma unroll
  for (int off=32; off; off>>=1) ls2 += __shfl_down(ls2, off, 64);
  if (lane==0) red[w] = ls2;
  __syncthreads();
  const float Z2 = red[0]+red[1]+red[2]+red[3];
  float* y = out1 + (size_t)(b*PREF_ + step)*V_;
  short* ab = Abuf + (size_t)b*KA_;
  #pragma unroll
  for (int i=0;i<8;i++){
    float4 y4; y4.x = lv[4*i]/Z2; y4.y = lv[4*i+1]/Z2; y4.z = lv[4*i+2]/Z2; y4.w = lv[4*i+3]/Z2;
    ((float4*)y)[t + 256*i] = y4;
    short4 s4; s4.x=f2bf(y4.x); s4.y=f2bf(y4.y); s4.z=f2bf(y4.z); s4.w=f2bf(y4.w);
    *(short4*)(ab + 4*(t + 256*i)) = s4;
  }
}

// ---------------- host ----------------
extern "C" void kernel_launch(void* const* d_in, const int* in_sizes, int n_in,
                              void* d_out, int out_size, void* d_ws, size_t ws_size,
                              hipStream_t stream)
{
  (void)in_sizes; (void)n_in; (void)out_size; (void)ws_size;
  const int*   context   = (const int*)  d_in[0];
  const int*   ctx_len   = (const int*)  d_in[1];
  const float* pv_m      = (const float*)d_in[2];
  const float* pv_mask   = (const float*)d_in[3];
  const int*   ar_len    = (const int*)  d_in[5];
  const int*   tp_path   = (const int*)  d_in[6];
  const int*   tp_len    = (const int*)  d_in[7];
  const float* tp_hidden = (const float*)d_in[8];
  const float* ar_hidden = (const float*)d_in[9];
  const float* E_ctx     = (const float*)d_in[10];
  const float* W_p       = (const float*)d_in[11];
  const float* E_topic   = (const float*)d_in[12];
  const float* W_q       = (const float*)d_in[13];
  const float* W_k       = (const float*)d_in[14];
  const float* W_v       = (const float*)d_in[15];
  const float* W_o       = (const float*)d_in[16];
  const float* gen_W     = (const float*)d_in[17];
  const float* gen_b     = (const float*)d_in[18];
  const int*   glo2loc   = (const int*)  d_in[19];

  float* out0 = (float*)d_out;
  float* out1 = out0 + (size_t)B_*PREF_*V_;

  // ---- workspace layout ----
  short* sw      = (short*)d_ws;
  short* EtM_pk  = sw;  sw += (size_t)8192*1024;     // E_topic @ Wq @ Wk^T, packed
  short* WoStack = sw;  sw += (size_t)KA_*1024;      // [E_topic@Wo ; Wv@Wo], packed
  short* genW_pk = sw;  sw += (size_t)1024*8192;
  short* Abuf    = sw;  sw += (size_t)B_*KA_;        // [y | asrc] bf16
  short* dtan    = sw;  sw += (size_t)B_*H_;
  short* src_bf  = sw;  sw += (size_t)B_*SP_*H_;     // materialized src_hidden bf16
  short* pvm_bf  = src_bf;                            // setup-only aliases (freed by src_build)
  short* Wp_pk   = src_bf + (size_t)1024*8192;
  float* fw      = (float*)sw;
  float* smask   = fw;  fw += B_*SP_;
  float* Mw      = fw;  fw += 1024*1024;
  float* pvh     = fw;  fw += 1024*1024;
  float* qk      = fw;  fw += B_*H_;                 // -- zero region start --
  float* decr    = fw;  fw += B_*H_;
  float* gen     = fw;  fw += (size_t)B_*V_;         // -- zero region end --
  float* part_o  = fw;  fw += (size_t)B_*8*H_;
  float* part_ml = fw;  fw += B_*8*2;
  float* cl      = fw;  fw += B_*544;
  const size_t zbytes = (size_t)(2*B_*H_ + B_*V_) * sizeof(float);

  // ---- one-time setup ----
  hipMemsetAsync(pvh, 0, (size_t)1024*1024*sizeof(float), stream);
  cast_bf  <<<dim3(2048), dim3(256), 0, stream>>>(pv_m, pvm_bf);          // 1024x8192
  cast_pack<<<dim3(8192), dim3(256), 0, stream>>>(W_p, Wp_pk, 1024);      // K=8192,N=1024
  bgemm<128,true,false><<<dim3(8,8,4), dim3(256), 0, stream>>>(
      pvm_bf, 8192, Wp_pk, 1024, pvh, 1024, 2048, nullptr);               // pv_hidden
  mgemm<true,false><<<dim3(8,8,1), dim3(256), 0, stream>>>(
      W_q, H_, W_k, H_, Mw, H_, H_);                                      // Mw = Wq@Wk^T
  mgemm<false,true><<<dim3(8,64,1), dim3(256), 0, stream>>>(
      E_topic, H_, Mw, H_, (float*)EtM_pk, H_, H_);                       // EtM packed
  mgemm<false,true><<<dim3(8,64,1), dim3(256), 0, stream>>>(
      E_topic, H_, W_o, H_, (float*)WoStack, H_, H_);                     // EtWo -> rows 0..8191
  mgemm<false,true><<<dim3(8,8,1), dim3(256), 0, stream>>>(
      W_v, H_, W_o, H_, (float*)(WoStack + (size_t)8192*1024), H_, H_);   // Wvo -> rows 8192..9215
  cast_pack<<<dim3(8192), dim3(256), 0, stream>>>(gen_W, genW_pk, 8192);  // K=1024,N=8192
  src_build<<<dim3(64,35), dim3(256), 0, stream>>>(
      E_ctx, context, ctx_len, pvh, pv_mask, tp_hidden, tp_len, ar_hidden, ar_len, src_bf, smask);
  abuf_init<<<dim3(36,64), dim3(256), 0, stream>>>(Abuf);

  // ---- decode loop ----
  for (int t = 0; t < PREF_; ++t){
    hipMemsetAsync(qk, 0, zbytes, stream);
    // qk = y @ EtM   (K=8192)
    bgemm<64,true,false><<<dim3(8,1,16), dim3(256), 0, stream>>>(
        Abuf, KA_, EtM_pk, H_, qk, H_, 512, nullptr);
    // attention
    attn_pass<<<dim3(64,8), dim3(256), 0, stream>>>(qk, src_bf, smask, part_o, part_ml);
    attn_combine<<<dim3(64), dim3(256), 0, stream>>>(part_o, part_ml, Abuf);
    // decr = [y|asrc] @ [EtWo;Wvo]  (K=9216)
    bgemm<64,true,false><<<dim3(8,1,18), dim3(256), 0, stream>>>(
        Abuf, KA_, WoStack, H_, decr, H_, 512, nullptr);
    tanhcast<<<dim3(64), dim3(256), 0, stream>>>(decr, dtan);
    // gen = tanh(decr) @ gen_W + b  (K=1024, N=8192)
    bgemm<64,true,true><<<dim3(64,1,2), dim3(256), 0, stream>>>(
        dtan, H_, genW_pk, V_, gen, V_, 512, gen_b);
    // copy logits
    copy_score<<<dim3(64,8), dim3(256), 0, stream>>>(dtan, src_bf, smask, cl);
    // softmax stats + p + scatter + sample (fused)
    fuse_out<<<dim3(64), dim3(256), 0, stream>>>(
        gen, cl, pv_m, context, glo2loc, tp_path, out0, out1, Abuf, t);
  }
}